// Round 1
// baseline (1096.093 us; speedup 1.0000x reference)
//
#include <hip/hip_runtime.h>
#include <stdint.h>

#define T_TOK 8192
#define HD 2048
#define NE 8
#define FD 1408
#define BM 128
#define BN 128
#define BK 64
#define MAXT 136            // max 128-row tiles: 16384/128 + 8
#define ROWS_CAP 17408      // 16384 + 8*128 padding

typedef unsigned short u16;
typedef __attribute__((ext_vector_type(8))) short bf16x8;   // 8 bf16 = 4 VGPRs
typedef __attribute__((ext_vector_type(4))) float f32x4;

__device__ __forceinline__ u16 f2bf(float f) {
  unsigned u = __float_as_uint(f);
  unsigned r = (u + 0x7fffu + ((u >> 16) & 1u)) >> 16;   // round-to-nearest-even
  return (u16)r;
}

__device__ __forceinline__ void async_copy16(const void* g, void* l) {
  __builtin_amdgcn_global_load_lds(
      (__attribute__((address_space(1))) void*)(uintptr_t)g,
      (__attribute__((address_space(3))) void*)(uintptr_t)l,
      16, 0, 0);
}

// ---------------- fp32 -> bf16 conversion ----------------
__global__ void k_convert(const float* __restrict__ src, u16* __restrict__ dst, int n4) {
  int i = blockIdx.x * blockDim.x + threadIdx.x;
  int stride = gridDim.x * blockDim.x;
  for (; i < n4; i += stride) {
    float4 v = ((const float4*)src)[i];
    ushort4 o;
    o.x = f2bf(v.x); o.y = f2bf(v.y); o.z = f2bf(v.z); o.w = f2bf(v.w);
    ((ushort4*)dst)[i] = o;
  }
}

// ---------------- router: logits, top-2, normalized weights ----------------
__global__ __launch_bounds__(256) void k_router(
    const float* __restrict__ x, const float* __restrict__ rw,
    int* __restrict__ meta, int* __restrict__ topk_idx, float* __restrict__ topk_w)
{
  int t = blockIdx.x;
  int lane = threadIdx.x & 63;
  int wave = threadIdx.x >> 6;       // wave w handles experts 2w, 2w+1
  const float4* xr = (const float4*)(x + (size_t)t * HD);
  const float4* w0 = (const float4*)(rw + (size_t)(wave * 2) * HD);
  const float4* w1 = (const float4*)(rw + (size_t)(wave * 2 + 1) * HD);
  float a0 = 0.f, a1 = 0.f;
  for (int i = lane; i < HD / 4; i += 64) {
    float4 xv = xr[i], v0 = w0[i], v1 = w1[i];
    a0 += xv.x * v0.x + xv.y * v0.y + xv.z * v0.z + xv.w * v0.w;
    a1 += xv.x * v1.x + xv.y * v1.y + xv.z * v1.z + xv.w * v1.w;
  }
#pragma unroll
  for (int off = 32; off > 0; off >>= 1) {
    a0 += __shfl_down(a0, off);
    a1 += __shfl_down(a1, off);
  }
  __shared__ float lg[NE];
  if (lane == 0) { lg[wave * 2] = a0; lg[wave * 2 + 1] = a1; }
  __syncthreads();
  if (threadIdx.x == 0) {
    float m1 = lg[0], m2 = -3.4e38f;
    int i1 = 0, i2 = 0;
    for (int e = 1; e < NE; e++) {
      float v = lg[e];
      if (v > m1)      { m2 = m1; i2 = i1; m1 = v; i1 = e; }
      else if (v > m2) { m2 = v; i2 = e; }
    }
    // normalized top-2 weights == 2-way softmax of top-2 logits
    float wA = 1.f / (1.f + expf(m2 - m1));
    float wB = 1.f - wA;
    topk_idx[t * 2] = i1; topk_idx[t * 2 + 1] = i2;
    topk_w[t * 2] = wA;   topk_w[t * 2 + 1] = wB;
    atomicAdd(&meta[i1], 1);
    atomicAdd(&meta[i2], 1);
  }
}

// ---------------- offsets + tile descriptors + zero row arrays ----------------
__global__ void k_meta(int* __restrict__ meta, int* __restrict__ row_token,
                       float* __restrict__ row_weight) {
  for (int i = threadIdx.x; i < ROWS_CAP; i += blockDim.x) {
    row_token[i] = 0;        // padding rows: token 0, weight 0 -> adds exactly +0.0
    row_weight[i] = 0.f;
  }
  __syncthreads();
  if (threadIdx.x == 0) {
    int off = 0, nt = 0;
    for (int e = 0; e < NE; e++) {
      int c = meta[e];               // count from router
      meta[16 + e] = off;            // scatter cursor
      int tiles = (c + BM - 1) / BM;
      for (int i = 0; i < tiles; i++) {
        meta[64 + nt] = e;           // tile -> expert
        meta[256 + nt] = off + i * BM; // tile -> row0
        nt++;
      }
      off += tiles * BM;             // expert regions padded to 128
    }
    meta[8] = nt;                    // total tiles
  }
}

// ---------------- scatter rows into per-expert regions ----------------
__global__ void k_scatter(const int* __restrict__ topk_idx, const float* __restrict__ topk_w,
                          int* __restrict__ meta, int* __restrict__ row_token,
                          float* __restrict__ row_weight) {
  int t = blockIdx.x * blockDim.x + threadIdx.x;
  if (t >= T_TOK) return;
#pragma unroll
  for (int s = 0; s < 2; s++) {
    int e = topk_idx[t * 2 + s];
    int p = atomicAdd(&meta[16 + e], 1);
    row_token[p] = t;
    row_weight[p] = topk_w[t * 2 + s];
  }
}

// ---------------- grouped GEMM1: h = silu(x@gate^T) * (x@up^T), bf16 out ----------------
__global__ __launch_bounds__(256, 2) void k_gemm1(
    const u16* __restrict__ xb, const u16* __restrict__ gwb, const u16* __restrict__ uwb,
    const int* __restrict__ meta, const int* __restrict__ row_token, u16* __restrict__ hb)
{
  int total = meta[8];
  int tile = blockIdx.x;
  if (tile >= total) return;
  int e = meta[64 + tile];
  int row0 = meta[256 + tile];
  int ntile = blockIdx.y;

  __shared__ u16 As[BM * BK];   // XOR-swizzled at 16B-chunk granularity
  __shared__ u16 Bg[BN * BK];
  __shared__ u16 Bu[BN * BK];

  int lane = threadIdx.x & 63;
  int wave = threadIdx.x >> 6;
  int wr = wave >> 1, wc = wave & 1;

  // Staging plan: each wave-issue fills 8 rows (8 chunks/row). Lane i -> row
  // base+i/8, slot i&7; slot s of row r holds chunk c = s ^ (r&7) (XOR swizzle).
  const u16* aG[4]; const u16* gG[4]; const u16* uG[4];
  unsigned ldsOff[4];
#pragma unroll
  for (int j = 0; j < 4; j++) {
    int r = wave * 32 + j * 8 + (lane >> 3);
    int c = (lane & 7) ^ (r & 7);
    int tok = row_token[row0 + r];
    aG[j] = xb + (size_t)tok * HD + c * 8;
    int nrow = ntile * BN + r;
    size_t wof = ((size_t)e * FD + nrow) * HD + c * 8;
    gG[j] = gwb + wof;
    uG[j] = uwb + wof;
    ldsOff[j] = (unsigned)(wave * 32 + j * 8) * 128;  // wave-uniform LDS base
  }

  f32x4 accG[4][4] = {};
  f32x4 accU[4][4] = {};

  for (int kt = 0; kt < HD / BK; kt++) {
    int ko = kt * BK;
#pragma unroll
    for (int j = 0; j < 4; j++) async_copy16(aG[j] + ko, (char*)As + ldsOff[j]);
#pragma unroll
    for (int j = 0; j < 4; j++) async_copy16(gG[j] + ko, (char*)Bg + ldsOff[j]);
#pragma unroll
    for (int j = 0; j < 4; j++) async_copy16(uG[j] + ko, (char*)Bu + ldsOff[j]);
    __syncthreads();
#pragma unroll
    for (int kk = 0; kk < 2; kk++) {
      bf16x8 av[4], gv[4], uv[4];
#pragma unroll
      for (int mi = 0; mi < 4; mi++) {
        int r = wr * 64 + mi * 16 + (lane & 15);
        int slot = (kk * 4 + (lane >> 4)) ^ (r & 7);
        av[mi] = *(const bf16x8*)((const char*)As + (unsigned)(r * 8 + slot) * 16);
      }
#pragma unroll
      for (int ni = 0; ni < 4; ni++) {
        int r = wc * 64 + ni * 16 + (lane & 15);
        int slot = (kk * 4 + (lane >> 4)) ^ (r & 7);
        gv[ni] = *(const bf16x8*)((const char*)Bg + (unsigned)(r * 8 + slot) * 16);
        uv[ni] = *(const bf16x8*)((const char*)Bu + (unsigned)(r * 8 + slot) * 16);
      }
#pragma unroll
      for (int mi = 0; mi < 4; mi++)
#pragma unroll
        for (int ni = 0; ni < 4; ni++) {
          accG[mi][ni] = __builtin_amdgcn_mfma_f32_16x16x32_bf16(av[mi], gv[ni], accG[mi][ni], 0, 0, 0);
          accU[mi][ni] = __builtin_amdgcn_mfma_f32_16x16x32_bf16(av[mi], uv[ni], accU[mi][ni], 0, 0, 0);
        }
    }
    __syncthreads();
  }

  // epilogue: silu(g)*u -> bf16 h. D layout: col=lane&15, row=(lane>>4)*4+reg
#pragma unroll
  for (int mi = 0; mi < 4; mi++) {
#pragma unroll
    for (int r = 0; r < 4; r++) {
      int row = row0 + wr * 64 + mi * 16 + (lane >> 4) * 4 + r;
      u16* hrow = hb + (size_t)row * FD + ntile * BN + wc * 64 + (lane & 15);
#pragma unroll
      for (int ni = 0; ni < 4; ni++) {
        float g = accG[mi][ni][r];
        float u = accU[mi][ni][r];
        float s = g / (1.f + __expf(-g));
        hrow[ni * 16] = f2bf(s * u);
      }
    }
  }
}

// ---------------- grouped GEMM2: out[token] += weight * (h @ down^T) ----------------
__global__ __launch_bounds__(256, 2) void k_gemm2(
    const u16* __restrict__ hb, const u16* __restrict__ dwb,
    const int* __restrict__ meta, const int* __restrict__ row_token,
    const float* __restrict__ row_weight, float* __restrict__ out)
{
  int total = meta[8];
  int tile = blockIdx.x;
  if (tile >= total) return;
  int e = meta[64 + tile];
  int row0 = meta[256 + tile];
  int ntile = blockIdx.y;

  __shared__ u16 As[BM * BK];
  __shared__ u16 Bs[BN * BK];

  int lane = threadIdx.x & 63;
  int wave = threadIdx.x >> 6;
  int wr = wave >> 1, wc = wave & 1;

  const u16* aG[4]; const u16* bG[4];
  unsigned ldsOff[4];
#pragma unroll
  for (int j = 0; j < 4; j++) {
    int r = wave * 32 + j * 8 + (lane >> 3);
    int c = (lane & 7) ^ (r & 7);
    aG[j] = hb + (size_t)(row0 + r) * FD + c * 8;
    int nrow = ntile * BN + r;
    bG[j] = dwb + ((size_t)e * HD + nrow) * FD + c * 8;
    ldsOff[j] = (unsigned)(wave * 32 + j * 8) * 128;
  }

  f32x4 acc[4][4] = {};

  for (int kt = 0; kt < FD / BK; kt++) {
    int ko = kt * BK;
#pragma unroll
    for (int j = 0; j < 4; j++) async_copy16(aG[j] + ko, (char*)As + ldsOff[j]);
#pragma unroll
    for (int j = 0; j < 4; j++) async_copy16(bG[j] + ko, (char*)Bs + ldsOff[j]);
    __syncthreads();
#pragma unroll
    for (int kk = 0; kk < 2; kk++) {
      bf16x8 av[4], bv[4];
#pragma unroll
      for (int mi = 0; mi < 4; mi++) {
        int r = wr * 64 + mi * 16 + (lane & 15);
        int slot = (kk * 4 + (lane >> 4)) ^ (r & 7);
        av[mi] = *(const bf16x8*)((const char*)As + (unsigned)(r * 8 + slot) * 16);
      }
#pragma unroll
      for (int ni = 0; ni < 4; ni++) {
        int r = wc * 64 + ni * 16 + (lane & 15);
        int slot = (kk * 4 + (lane >> 4)) ^ (r & 7);
        bv[ni] = *(const bf16x8*)((const char*)Bs + (unsigned)(r * 8 + slot) * 16);
      }
#pragma unroll
      for (int mi = 0; mi < 4; mi++)
#pragma unroll
        for (int ni = 0; ni < 4; ni++)
          acc[mi][ni] = __builtin_amdgcn_mfma_f32_16x16x32_bf16(av[mi], bv[ni], acc[mi][ni], 0, 0, 0);
    }
    __syncthreads();
  }

  // epilogue: weighted atomic accumulate into out (2 commutative adds/element)
#pragma unroll
  for (int mi = 0; mi < 4; mi++) {
#pragma unroll
    for (int r = 0; r < 4; r++) {
      int grow = row0 + wr * 64 + mi * 16 + (lane >> 4) * 4 + r;
      int tok = row_token[grow];
      float wgt = row_weight[grow];
      float* orow = out + (size_t)tok * HD + ntile * BN + wc * 64 + (lane & 15);
#pragma unroll
      for (int ni = 0; ni < 4; ni++)
        atomicAdd(&orow[ni * 16], wgt * acc[mi][ni][r]);
    }
  }
}

extern "C" void kernel_launch(void* const* d_in, const int* in_sizes, int n_in,
                              void* d_out, int out_size, void* d_ws, size_t ws_size,
                              hipStream_t stream) {
  const float* x  = (const float*)d_in[0];
  const float* rw = (const float*)d_in[1];
  const float* gw = (const float*)d_in[2];
  const float* uw = (const float*)d_in[3];
  const float* dw = (const float*)d_in[4];
  float* out = (float*)d_out;

  char* w = (char*)d_ws;
  int*   meta       = (int*)w;                                   // 4KB meta block
  int*   row_token  = (int*)(w + 4096);
  float* row_weight = (float*)(w + 4096 + ROWS_CAP * 4);
  int*   topk_idx   = (int*)(w + 4096 + 2 * ROWS_CAP * 4);
  float* topk_w     = (float*)(w + 4096 + 2 * ROWS_CAP * 4 + T_TOK * 2 * 4);
  size_t off = (size_t)1 << 20;
  u16* xb  = (u16*)(w + off); off += (size_t)T_TOK * HD * 2;     // 32 MB
  u16* gwb = (u16*)(w + off); off += (size_t)NE * FD * HD * 2;   // 44 MB
  u16* uwb = (u16*)(w + off); off += (size_t)NE * FD * HD * 2;   // 44 MB
  u16* dwb = (u16*)(w + off); off += (size_t)NE * HD * FD * 2;   // 44 MB
  u16* hb  = (u16*)(w + off);                                    // 46.8 MB

  hipMemsetAsync(d_out, 0, (size_t)out_size * 4, stream);
  hipMemsetAsync(meta, 0, 64, stream);   // counts + total

  k_convert<<<4096, 256, 0, stream>>>(x,  xb,  T_TOK * HD / 4);
  k_convert<<<4096, 256, 0, stream>>>(gw, gwb, NE * FD * HD / 4);
  k_convert<<<4096, 256, 0, stream>>>(uw, uwb, NE * FD * HD / 4);
  k_convert<<<4096, 256, 0, stream>>>(dw, dwb, NE * HD * FD / 4);

  k_router<<<T_TOK, 256, 0, stream>>>(x, rw, meta, topk_idx, topk_w);
  k_meta<<<1, 256, 0, stream>>>(meta, row_token, row_weight);
  k_scatter<<<32, 256, 0, stream>>>(topk_idx, topk_w, meta, row_token, row_weight);

  k_gemm1<<<dim3(MAXT, FD / BN), 256, 0, stream>>>(xb, gwb, uwb, meta, row_token, hb);
  k_gemm2<<<dim3(MAXT, HD / BN), 256, 0, stream>>>(hb, dwb, meta, row_token, row_weight, out);
}

// Round 2
// 940.605 us; speedup vs baseline: 1.1653x; 1.1653x over previous
//
#include <hip/hip_runtime.h>
#include <stdint.h>

#define T_TOK 8192
#define HD 2048
#define NE 8
#define FD 1408
#define BM 128
#define BN 128
#define BK 64
#define MAXT 136            // max 128-row tiles: 16384/128 + 8
#define ROWS_CAP 17408      // 16384 + 8*128 padding

typedef unsigned short u16;
typedef __attribute__((ext_vector_type(8))) short bf16x8;   // 8 bf16 = 4 VGPRs
typedef __attribute__((ext_vector_type(4))) float f32x4;

__device__ __forceinline__ u16 f2bf(float f) {
  unsigned u = __float_as_uint(f);
  unsigned r = (u + 0x7fffu + ((u >> 16) & 1u)) >> 16;   // round-to-nearest-even
  return (u16)r;
}
__device__ __forceinline__ float bflo(unsigned u) { return __uint_as_float(u << 16); }
__device__ __forceinline__ float bfhi(unsigned u) { return __uint_as_float(u & 0xffff0000u); }

__device__ __forceinline__ void async_copy16(const void* g, void* l) {
  __builtin_amdgcn_global_load_lds(
      (__attribute__((address_space(1))) void*)(uintptr_t)g,
      (__attribute__((address_space(3))) void*)(uintptr_t)l,
      16, 0, 0);
}

// ---------------- fp32 -> bf16 conversion (all 4 tensors, one kernel) ----------------
__global__ void k_convert_all(const float* __restrict__ x, const float* __restrict__ gw,
                              const float* __restrict__ uw, const float* __restrict__ dw,
                              u16* __restrict__ xb, u16* __restrict__ gwb,
                              u16* __restrict__ uwb, u16* __restrict__ dwb) {
  const long n_x = (long)T_TOK * HD / 4;
  const long n_w = (long)NE * FD * HD / 4;
  const long total = n_x + 3 * n_w;
  long stride = (long)gridDim.x * blockDim.x;
  for (long i = (long)blockIdx.x * blockDim.x + threadIdx.x; i < total; i += stride) {
    const float* s; u16* d; long j = i;
    if (j < n_x) { s = x; d = xb; }
    else {
      j -= n_x;
      if (j < n_w) { s = gw; d = gwb; }
      else {
        j -= n_w;
        if (j < n_w) { s = uw; d = uwb; }
        else { j -= n_w; s = dw; d = dwb; }
      }
    }
    float4 v = ((const float4*)s)[j];
    ushort4 o;
    o.x = f2bf(v.x); o.y = f2bf(v.y); o.z = f2bf(v.z); o.w = f2bf(v.w);
    ((ushort4*)d)[j] = o;
  }
}

// ---------------- router: logits, top-2, normalized weights ----------------
__global__ __launch_bounds__(256) void k_router(
    const float* __restrict__ x, const float* __restrict__ rw,
    int* __restrict__ meta, int* __restrict__ topk_idx, float* __restrict__ topk_w)
{
  int t = blockIdx.x;
  int lane = threadIdx.x & 63;
  int wave = threadIdx.x >> 6;       // wave w handles experts 2w, 2w+1
  const float4* xr = (const float4*)(x + (size_t)t * HD);
  const float4* w0 = (const float4*)(rw + (size_t)(wave * 2) * HD);
  const float4* w1 = (const float4*)(rw + (size_t)(wave * 2 + 1) * HD);
  float a0 = 0.f, a1 = 0.f;
  for (int i = lane; i < HD / 4; i += 64) {
    float4 xv = xr[i], v0 = w0[i], v1 = w1[i];
    a0 += xv.x * v0.x + xv.y * v0.y + xv.z * v0.z + xv.w * v0.w;
    a1 += xv.x * v1.x + xv.y * v1.y + xv.z * v1.z + xv.w * v1.w;
  }
#pragma unroll
  for (int off = 32; off > 0; off >>= 1) {
    a0 += __shfl_down(a0, off);
    a1 += __shfl_down(a1, off);
  }
  __shared__ float lg[NE];
  if (lane == 0) { lg[wave * 2] = a0; lg[wave * 2 + 1] = a1; }
  __syncthreads();
  if (threadIdx.x == 0) {
    float m1 = lg[0], m2 = -3.4e38f;
    int i1 = 0, i2 = 0;
    for (int e = 1; e < NE; e++) {
      float v = lg[e];
      if (v > m1)      { m2 = m1; i2 = i1; m1 = v; i1 = e; }
      else if (v > m2) { m2 = v; i2 = e; }
    }
    // normalized top-2 weights == 2-way softmax of top-2 logits
    float wA = 1.f / (1.f + expf(m2 - m1));
    float wB = 1.f - wA;
    topk_idx[t * 2] = i1; topk_idx[t * 2 + 1] = i2;
    topk_w[t * 2] = wA;   topk_w[t * 2 + 1] = wB;
    atomicAdd(&meta[i1], 1);
    atomicAdd(&meta[i2], 1);
  }
}

// ---------------- offsets + tile descriptors + zero row arrays ----------------
__global__ void k_meta(int* __restrict__ meta, int* __restrict__ row_token) {
  for (int i = threadIdx.x; i < ROWS_CAP; i += blockDim.x)
    row_token[i] = 0;        // padding rows: valid token 0 (their Y rows are never read)
  __syncthreads();
  if (threadIdx.x == 0) {
    int off = 0, nt = 0;
    for (int e = 0; e < NE; e++) {
      int c = meta[e];               // count from router
      meta[16 + e] = off;            // scatter cursor
      int tiles = (c + BM - 1) / BM;
      for (int i = 0; i < tiles; i++) {
        meta[64 + nt] = e;             // tile -> expert
        meta[256 + nt] = off + i * BM; // tile -> row0
        nt++;
      }
      off += tiles * BM;             // expert regions padded to 128
    }
    meta[8] = nt;                    // total tiles
  }
}

// ---------------- scatter rows into per-expert regions (+ inverse map) ----------------
__global__ void k_scatter(const int* __restrict__ topk_idx,
                          int* __restrict__ meta, int* __restrict__ row_token,
                          int* __restrict__ tokrow) {
  int t = blockIdx.x * blockDim.x + threadIdx.x;
  if (t >= T_TOK) return;
#pragma unroll
  for (int s = 0; s < 2; s++) {
    int e = topk_idx[t * 2 + s];
    int p = atomicAdd(&meta[16 + e], 1);
    row_token[p] = t;
    tokrow[t * 2 + s] = p;           // inverse map: token slot -> routed row
  }
}

// ---------------- grouped GEMM1: h = silu(x@gate^T) * (x@up^T), bf16 out ----------------
__global__ __launch_bounds__(256, 2) void k_gemm1(
    const u16* __restrict__ xb, const u16* __restrict__ gwb, const u16* __restrict__ uwb,
    const int* __restrict__ meta, const int* __restrict__ row_token, u16* __restrict__ hb)
{
  int total = meta[8];
  int tile = blockIdx.x;
  if (tile >= total) return;
  int e = meta[64 + tile];
  int row0 = meta[256 + tile];
  int ntile = blockIdx.y;

  __shared__ u16 As[BM * BK];   // XOR-swizzled at 16B-chunk granularity
  __shared__ u16 Bg[BN * BK];
  __shared__ u16 Bu[BN * BK];

  int lane = threadIdx.x & 63;
  int wave = threadIdx.x >> 6;
  int wr = wave >> 1, wc = wave & 1;

  const u16* aG[4]; const u16* gG[4]; const u16* uG[4];
  unsigned ldsOff[4];
#pragma unroll
  for (int j = 0; j < 4; j++) {
    int r = wave * 32 + j * 8 + (lane >> 3);
    int c = (lane & 7) ^ (r & 7);
    int tok = row_token[row0 + r];
    aG[j] = xb + (size_t)tok * HD + c * 8;
    int nrow = ntile * BN + r;
    size_t wof = ((size_t)e * FD + nrow) * HD + c * 8;
    gG[j] = gwb + wof;
    uG[j] = uwb + wof;
    ldsOff[j] = (unsigned)(wave * 32 + j * 8) * 128;  // wave-uniform LDS base
  }

  f32x4 accG[4][4] = {};
  f32x4 accU[4][4] = {};

  for (int kt = 0; kt < HD / BK; kt++) {
    int ko = kt * BK;
#pragma unroll
    for (int j = 0; j < 4; j++) async_copy16(aG[j] + ko, (char*)As + ldsOff[j]);
#pragma unroll
    for (int j = 0; j < 4; j++) async_copy16(gG[j] + ko, (char*)Bg + ldsOff[j]);
#pragma unroll
    for (int j = 0; j < 4; j++) async_copy16(uG[j] + ko, (char*)Bu + ldsOff[j]);
    __syncthreads();
#pragma unroll
    for (int kk = 0; kk < 2; kk++) {
      bf16x8 av[4], gv[4], uv[4];
#pragma unroll
      for (int mi = 0; mi < 4; mi++) {
        int r = wr * 64 + mi * 16 + (lane & 15);
        int slot = (kk * 4 + (lane >> 4)) ^ (r & 7);
        av[mi] = *(const bf16x8*)((const char*)As + (unsigned)(r * 8 + slot) * 16);
      }
#pragma unroll
      for (int ni = 0; ni < 4; ni++) {
        int r = wc * 64 + ni * 16 + (lane & 15);
        int slot = (kk * 4 + (lane >> 4)) ^ (r & 7);
        gv[ni] = *(const bf16x8*)((const char*)Bg + (unsigned)(r * 8 + slot) * 16);
        uv[ni] = *(const bf16x8*)((const char*)Bu + (unsigned)(r * 8 + slot) * 16);
      }
#pragma unroll
      for (int mi = 0; mi < 4; mi++)
#pragma unroll
        for (int ni = 0; ni < 4; ni++) {
          accG[mi][ni] = __builtin_amdgcn_mfma_f32_16x16x32_bf16(av[mi], gv[ni], accG[mi][ni], 0, 0, 0);
          accU[mi][ni] = __builtin_amdgcn_mfma_f32_16x16x32_bf16(av[mi], uv[ni], accU[mi][ni], 0, 0, 0);
        }
    }
    __syncthreads();
  }

  // epilogue: silu(g)*u -> bf16 h. D layout: col=lane&15, row=(lane>>4)*4+reg
#pragma unroll
  for (int mi = 0; mi < 4; mi++) {
#pragma unroll
    for (int r = 0; r < 4; r++) {
      int row = row0 + wr * 64 + mi * 16 + (lane >> 4) * 4 + r;
      u16* hrow = hb + (size_t)row * FD + ntile * BN + wc * 64 + (lane & 15);
#pragma unroll
      for (int ni = 0; ni < 4; ni++) {
        float g = accG[mi][ni][r];
        float u = accU[mi][ni][r];
        float s = g / (1.f + __expf(-g));
        hrow[ni * 16] = f2bf(s * u);
      }
    }
  }
}

// ---------------- grouped GEMM2: Y = h @ down^T (row space, bf16, plain stores) ----------------
__global__ __launch_bounds__(256, 4) void k_gemm2(
    const u16* __restrict__ hb, const u16* __restrict__ dwb,
    const int* __restrict__ meta, u16* __restrict__ Y)
{
  int total = meta[8];
  int tile = blockIdx.x;
  if (tile >= total) return;
  int e = meta[64 + tile];
  int row0 = meta[256 + tile];
  int ntile = blockIdx.y;

  __shared__ u16 As[BM * BK];
  __shared__ u16 Bs[BN * BK];

  int lane = threadIdx.x & 63;
  int wave = threadIdx.x >> 6;
  int wr = wave >> 1, wc = wave & 1;

  const u16* aG[4]; const u16* bG[4];
  unsigned ldsOff[4];
#pragma unroll
  for (int j = 0; j < 4; j++) {
    int r = wave * 32 + j * 8 + (lane >> 3);
    int c = (lane & 7) ^ (r & 7);
    aG[j] = hb + (size_t)(row0 + r) * FD + c * 8;
    int nrow = ntile * BN + r;
    bG[j] = dwb + ((size_t)e * HD + nrow) * FD + c * 8;
    ldsOff[j] = (unsigned)(wave * 32 + j * 8) * 128;
  }

  f32x4 acc[4][4] = {};

  for (int kt = 0; kt < FD / BK; kt++) {
    int ko = kt * BK;
#pragma unroll
    for (int j = 0; j < 4; j++) async_copy16(aG[j] + ko, (char*)As + ldsOff[j]);
#pragma unroll
    for (int j = 0; j < 4; j++) async_copy16(bG[j] + ko, (char*)Bs + ldsOff[j]);
    __syncthreads();
#pragma unroll
    for (int kk = 0; kk < 2; kk++) {
      bf16x8 av[4], bv[4];
#pragma unroll
      for (int mi = 0; mi < 4; mi++) {
        int r = wr * 64 + mi * 16 + (lane & 15);
        int slot = (kk * 4 + (lane >> 4)) ^ (r & 7);
        av[mi] = *(const bf16x8*)((const char*)As + (unsigned)(r * 8 + slot) * 16);
      }
#pragma unroll
      for (int ni = 0; ni < 4; ni++) {
        int r = wc * 64 + ni * 16 + (lane & 15);
        int slot = (kk * 4 + (lane >> 4)) ^ (r & 7);
        bv[ni] = *(const bf16x8*)((const char*)Bs + (unsigned)(r * 8 + slot) * 16);
      }
#pragma unroll
      for (int mi = 0; mi < 4; mi++)
#pragma unroll
        for (int ni = 0; ni < 4; ni++)
          acc[mi][ni] = __builtin_amdgcn_mfma_f32_16x16x32_bf16(av[mi], bv[ni], acc[mi][ni], 0, 0, 0);
    }
    __syncthreads();
  }

  // epilogue: plain bf16 stores into row-space Y (no atomics)
#pragma unroll
  for (int mi = 0; mi < 4; mi++) {
#pragma unroll
    for (int r = 0; r < 4; r++) {
      int grow = row0 + wr * 64 + mi * 16 + (lane >> 4) * 4 + r;
      u16* yrow = Y + (size_t)grow * HD + ntile * BN + wc * 64 + (lane & 15);
#pragma unroll
      for (int ni = 0; ni < 4; ni++)
        yrow[ni * 16] = f2bf(acc[mi][ni][r]);
    }
  }
}

// ---------------- combine: out[t] = wA*Y[rowA] + wB*Y[rowB] ----------------
__global__ __launch_bounds__(256) void k_combine(
    const u16* __restrict__ Y, const int* __restrict__ tokrow,
    const float* __restrict__ topk_w, float* __restrict__ out)
{
  int t = blockIdx.x;
  int i = threadIdx.x;               // 256 threads x 8 cols = 2048
  int rA = tokrow[t * 2], rB = tokrow[t * 2 + 1];
  float wA = topk_w[t * 2], wB = topk_w[t * 2 + 1];
  uint4 a = *(const uint4*)(Y + (size_t)rA * HD + i * 8);
  uint4 b = *(const uint4*)(Y + (size_t)rB * HD + i * 8);
  float4 o0, o1;
  o0.x = wA * bflo(a.x) + wB * bflo(b.x);
  o0.y = wA * bfhi(a.x) + wB * bfhi(b.x);
  o0.z = wA * bflo(a.y) + wB * bflo(b.y);
  o0.w = wA * bfhi(a.y) + wB * bfhi(b.y);
  o1.x = wA * bflo(a.z) + wB * bflo(b.z);
  o1.y = wA * bfhi(a.z) + wB * bfhi(b.z);
  o1.z = wA * bflo(a.w) + wB * bflo(b.w);
  o1.w = wA * bfhi(a.w) + wB * bfhi(b.w);
  float* op = out + (size_t)t * HD + i * 8;
  *(float4*)op = o0;
  *(float4*)(op + 4) = o1;
}

extern "C" void kernel_launch(void* const* d_in, const int* in_sizes, int n_in,
                              void* d_out, int out_size, void* d_ws, size_t ws_size,
                              hipStream_t stream) {
  const float* x  = (const float*)d_in[0];
  const float* rw = (const float*)d_in[1];
  const float* gw = (const float*)d_in[2];
  const float* uw = (const float*)d_in[3];
  const float* dw = (const float*)d_in[4];
  float* out = (float*)d_out;

  char* w = (char*)d_ws;
  int*   meta      = (int*)w;                                    // 4KB meta block
  int*   row_token = (int*)(w + 4096);
  int*   topk_idx  = (int*)(w + 4096 + ROWS_CAP * 4);
  float* topk_w    = (float*)(w + 4096 + ROWS_CAP * 4 + T_TOK * 2 * 4);
  int*   tokrow    = (int*)(w + 4096 + ROWS_CAP * 4 + T_TOK * 4 * 4);
  size_t off = (size_t)1 << 20;
  u16* xb  = (u16*)(w + off); off += (size_t)T_TOK * HD * 2;     // 33.5 MB
  u16* gwb = (u16*)(w + off); off += (size_t)NE * FD * HD * 2;   // 46.1 MB
  u16* uwb = (u16*)(w + off); off += (size_t)NE * FD * HD * 2;   // 46.1 MB
  u16* dwb = (u16*)(w + off); off += (size_t)NE * HD * FD * 2;   // 46.1 MB
  u16* hb  = (u16*)(w + off);                                    // 49.0 MB
  // Y (71.3 MB) aliases xb+gwb (79.7 MB) — both dead once gemm1 completes,
  // and the stream serializes gemm1 -> gemm2 -> combine.
  u16* Y = xb;

  hipMemsetAsync(meta, 0, 64, stream);   // expert counts + total-tiles

  k_convert_all<<<8192, 256, 0, stream>>>(x, gw, uw, dw, xb, gwb, uwb, dwb);

  k_router<<<T_TOK, 256, 0, stream>>>(x, rw, meta, topk_idx, topk_w);
  k_meta<<<1, 256, 0, stream>>>(meta, row_token);
  k_scatter<<<32, 256, 0, stream>>>(topk_idx, meta, row_token, tokrow);

  k_gemm1<<<dim3(MAXT, FD / BN), 256, 0, stream>>>(xb, gwb, uwb, meta, row_token, hb);
  k_gemm2<<<dim3(MAXT, HD / BN), 256, 0, stream>>>(hb, dwb, meta, Y);
  k_combine<<<T_TOK, 256, 0, stream>>>(Y, tokrow, topk_w, out);
}

// Round 3
// 746.552 us; speedup vs baseline: 1.4682x; 1.2599x over previous
//
#include <hip/hip_runtime.h>
#include <stdint.h>

#define T_TOK 8192
#define HD 2048
#define NE 8
#define FD 1408
#define BM 128
#define BN 128
#define BK 64
#define MAXT 136            // max 128-row tiles: 16384/128 + 8
#define ROWS_CAP 17408      // 16384 + 8*128 padding

typedef unsigned short u16;
typedef __attribute__((ext_vector_type(8))) short bf16x8;   // 8 bf16 = 4 VGPRs
typedef __attribute__((ext_vector_type(4))) float f32x4;

__device__ __forceinline__ u16 f2bf(float f) {
  unsigned u = __float_as_uint(f);
  unsigned r = (u + 0x7fffu + ((u >> 16) & 1u)) >> 16;   // round-to-nearest-even
  return (u16)r;
}
__device__ __forceinline__ float bflo(unsigned u) { return __uint_as_float(u << 16); }
__device__ __forceinline__ float bfhi(unsigned u) { return __uint_as_float(u & 0xffff0000u); }

__device__ __forceinline__ void async_copy16(const void* g, void* l) {
  __builtin_amdgcn_global_load_lds(
      (__attribute__((address_space(1))) void*)(uintptr_t)g,
      (__attribute__((address_space(3))) void*)(uintptr_t)l,
      16, 0, 0);
}

// ---------------- fp32 -> bf16 weight conversion (gate/up/down via blockIdx.y) ----------------
__global__ void k_convert_w(const float* __restrict__ gw, const float* __restrict__ uw,
                            const float* __restrict__ dw, u16* __restrict__ gwb,
                            u16* __restrict__ uwb, u16* __restrict__ dwb) {
  const long n_w = (long)NE * FD * HD / 4;
  const float* s; u16* d;
  if (blockIdx.y == 0)      { s = gw; d = gwb; }
  else if (blockIdx.y == 1) { s = uw; d = uwb; }
  else                      { s = dw; d = dwb; }
  long stride = (long)gridDim.x * blockDim.x;
  for (long j = (long)blockIdx.x * blockDim.x + threadIdx.x; j < n_w; j += stride) {
    float4 v = ((const float4*)s)[j];
    ushort4 o;
    o.x = f2bf(v.x); o.y = f2bf(v.y); o.z = f2bf(v.z); o.w = f2bf(v.w);
    ((ushort4*)d)[j] = o;
  }
}

// ---------------- router: logits, top-2, normalized weights; fused x->bf16 ----------------
__global__ __launch_bounds__(256) void k_router(
    const float* __restrict__ x, const float* __restrict__ rw, u16* __restrict__ xb,
    int* __restrict__ topk_idx, float* __restrict__ topk_w)
{
  int t = blockIdx.x;
  int tid = threadIdx.x;
  int lane = tid & 63;
  int wave = tid >> 6;               // wave w handles experts 2w, 2w+1
  const float4* xr = (const float4*)(x + (size_t)t * HD);
  const float4* w0 = (const float4*)(rw + (size_t)(wave * 2) * HD);
  const float4* w1 = (const float4*)(rw + (size_t)(wave * 2 + 1) * HD);
  float a0 = 0.f, a1 = 0.f;
  for (int i = lane; i < HD / 4; i += 64) {
    float4 xv = xr[i], v0 = w0[i], v1 = w1[i];
    a0 += xv.x * v0.x + xv.y * v0.y + xv.z * v0.z + xv.w * v0.w;
    a1 += xv.x * v1.x + xv.y * v1.y + xv.z * v1.z + xv.w * v1.w;
  }
  // fused x row -> bf16 (independent of the reduction; row is L1-hot)
  {
    float4 v0 = xr[tid * 2], v1 = xr[tid * 2 + 1];
    uint4 o;
    o.x = (unsigned)f2bf(v0.x) | ((unsigned)f2bf(v0.y) << 16);
    o.y = (unsigned)f2bf(v0.z) | ((unsigned)f2bf(v0.w) << 16);
    o.z = (unsigned)f2bf(v1.x) | ((unsigned)f2bf(v1.y) << 16);
    o.w = (unsigned)f2bf(v1.z) | ((unsigned)f2bf(v1.w) << 16);
    ((uint4*)(xb + (size_t)t * HD))[tid] = o;
  }
#pragma unroll
  for (int off = 32; off > 0; off >>= 1) {
    a0 += __shfl_down(a0, off);
    a1 += __shfl_down(a1, off);
  }
  __shared__ float lg[NE];
  if (lane == 0) { lg[wave * 2] = a0; lg[wave * 2 + 1] = a1; }
  __syncthreads();
  if (tid == 0) {
    float m1 = lg[0], m2 = -3.4e38f;
    int i1 = 0, i2 = 0;
    for (int e = 1; e < NE; e++) {
      float v = lg[e];
      if (v > m1)      { m2 = m1; i2 = i1; m1 = v; i1 = e; }
      else if (v > m2) { m2 = v; i2 = e; }
    }
    // normalized top-2 weights == 2-way softmax of top-2 logits
    float wA = 1.f / (1.f + expf(m2 - m1));
    float wB = 1.f - wA;
    topk_idx[t * 2] = i1; topk_idx[t * 2 + 1] = i2;
    topk_w[t * 2] = wA;   topk_w[t * 2 + 1] = wB;
  }
}

// ---------------- meta: histogram + offsets + tile descriptors (single block) ----------------
__global__ __launch_bounds__(256) void k_meta(const int* __restrict__ topk_idx,
                                              int* __restrict__ meta,
                                              int* __restrict__ row_token) {
  __shared__ int hist[NE];
  __shared__ int tstart[NE + 1];   // tile-index prefix per expert
  __shared__ int roff[NE];         // row-region offset per expert
  int tid = threadIdx.x;
  if (tid < NE) hist[tid] = 0;
  // zero row_token so padding rows map to token 0 (their Y rows are never read)
  for (int i = tid; i < ROWS_CAP; i += 256) row_token[i] = 0;
  __syncthreads();
  // register-local histogram: 64 items/thread, compare against each expert
  int cnt[NE] = {};
  for (int i = tid; i < 2 * T_TOK; i += 256) {
    int v = topk_idx[i];
#pragma unroll
    for (int e = 0; e < NE; e++) cnt[e] += (v == e);
  }
#pragma unroll
  for (int e = 0; e < NE; e++) if (cnt[e]) atomicAdd(&hist[e], cnt[e]);
  __syncthreads();
  if (tid == 0) {
    int off = 0, nt = 0;
    for (int e = 0; e < NE; e++) {
      int tiles = (hist[e] + BM - 1) / BM;
      roff[e] = off;
      tstart[e] = nt;
      nt += tiles;
      off += tiles * BM;           // expert regions padded to 128 rows
    }
    tstart[NE] = nt;
  }
  __syncthreads();
  int nt = tstart[NE];
  if (tid < NE) meta[16 + tid] = roff[tid];   // scatter cursors
  if (tid == 0) meta[8] = nt;                 // total tiles
  if (tid < nt) {
    int e = 0;
#pragma unroll
    for (int k = 1; k < NE; k++) e += (tid >= tstart[k]);
    meta[64 + tid] = e;                               // tile -> expert
    meta[256 + tid] = roff[e] + (tid - tstart[e]) * BM; // tile -> row0
  }
}

// ---------------- scatter: block-aggregated (8 global atomics per block) ----------------
__global__ __launch_bounds__(256) void k_scatter(const int* __restrict__ topk_idx,
                                                 int* __restrict__ meta,
                                                 int* __restrict__ row_token,
                                                 int* __restrict__ tokrow) {
  __shared__ int hist[NE], base[NE];
  int tid = threadIdx.x;
  if (tid < NE) hist[tid] = 0;
  __syncthreads();
  int t = blockIdx.x * 256 + tid;
  int e0 = topk_idx[t * 2], e1 = topk_idx[t * 2 + 1];
  int r0 = atomicAdd(&hist[e0], 1);   // local rank within block (LDS, fast)
  int r1 = atomicAdd(&hist[e1], 1);
  __syncthreads();
  if (tid < NE) base[tid] = atomicAdd(&meta[16 + tid], hist[tid]);  // 8 global atomics
  __syncthreads();
  int p0 = base[e0] + r0, p1 = base[e1] + r1;
  row_token[p0] = t; tokrow[t * 2] = p0;
  row_token[p1] = t; tokrow[t * 2 + 1] = p1;
}

// ---------------- grouped GEMM1: h = silu(x@gate^T) * (x@up^T), bf16 out ----------------
__global__ __launch_bounds__(256, 2) void k_gemm1(
    const u16* __restrict__ xb, const u16* __restrict__ gwb, const u16* __restrict__ uwb,
    const int* __restrict__ meta, const int* __restrict__ row_token, u16* __restrict__ hb)
{
  int total = meta[8];
  int tile = blockIdx.x;
  if (tile >= total) return;
  int e = meta[64 + tile];
  int row0 = meta[256 + tile];
  int ntile = blockIdx.y;

  __shared__ u16 As[BM * BK];   // XOR-swizzled at 16B-chunk granularity
  __shared__ u16 Bg[BN * BK];
  __shared__ u16 Bu[BN * BK];

  int lane = threadIdx.x & 63;
  int wave = threadIdx.x >> 6;
  int wr = wave >> 1, wc = wave & 1;

  const u16* aG[4]; const u16* gG[4]; const u16* uG[4];
  unsigned ldsOff[4];
#pragma unroll
  for (int j = 0; j < 4; j++) {
    int r = wave * 32 + j * 8 + (lane >> 3);
    int c = (lane & 7) ^ (r & 7);
    int tok = row_token[row0 + r];
    aG[j] = xb + (size_t)tok * HD + c * 8;
    int nrow = ntile * BN + r;
    size_t wof = ((size_t)e * FD + nrow) * HD + c * 8;
    gG[j] = gwb + wof;
    uG[j] = uwb + wof;
    ldsOff[j] = (unsigned)(wave * 32 + j * 8) * 128;  // wave-uniform LDS base
  }

  f32x4 accG[4][4] = {};
  f32x4 accU[4][4] = {};

  for (int kt = 0; kt < HD / BK; kt++) {
    int ko = kt * BK;
#pragma unroll
    for (int j = 0; j < 4; j++) async_copy16(aG[j] + ko, (char*)As + ldsOff[j]);
#pragma unroll
    for (int j = 0; j < 4; j++) async_copy16(gG[j] + ko, (char*)Bg + ldsOff[j]);
#pragma unroll
    for (int j = 0; j < 4; j++) async_copy16(uG[j] + ko, (char*)Bu + ldsOff[j]);
    __syncthreads();
#pragma unroll
    for (int kk = 0; kk < 2; kk++) {
      bf16x8 av[4], gv[4], uv[4];
#pragma unroll
      for (int mi = 0; mi < 4; mi++) {
        int r = wr * 64 + mi * 16 + (lane & 15);
        int slot = (kk * 4 + (lane >> 4)) ^ (r & 7);
        av[mi] = *(const bf16x8*)((const char*)As + (unsigned)(r * 8 + slot) * 16);
      }
#pragma unroll
      for (int ni = 0; ni < 4; ni++) {
        int r = wc * 64 + ni * 16 + (lane & 15);
        int slot = (kk * 4 + (lane >> 4)) ^ (r & 7);
        gv[ni] = *(const bf16x8*)((const char*)Bg + (unsigned)(r * 8 + slot) * 16);
        uv[ni] = *(const bf16x8*)((const char*)Bu + (unsigned)(r * 8 + slot) * 16);
      }
#pragma unroll
      for (int mi = 0; mi < 4; mi++)
#pragma unroll
        for (int ni = 0; ni < 4; ni++) {
          accG[mi][ni] = __builtin_amdgcn_mfma_f32_16x16x32_bf16(av[mi], gv[ni], accG[mi][ni], 0, 0, 0);
          accU[mi][ni] = __builtin_amdgcn_mfma_f32_16x16x32_bf16(av[mi], uv[ni], accU[mi][ni], 0, 0, 0);
        }
    }
    __syncthreads();
  }

  // epilogue: silu(g)*u -> bf16 h. D layout: col=lane&15, row=(lane>>4)*4+reg
#pragma unroll
  for (int mi = 0; mi < 4; mi++) {
#pragma unroll
    for (int r = 0; r < 4; r++) {
      int row = row0 + wr * 64 + mi * 16 + (lane >> 4) * 4 + r;
      u16* hrow = hb + (size_t)row * FD + ntile * BN + wc * 64 + (lane & 15);
#pragma unroll
      for (int ni = 0; ni < 4; ni++) {
        float g = accG[mi][ni][r];
        float u = accU[mi][ni][r];
        float s = g / (1.f + __expf(-g));
        hrow[ni * 16] = f2bf(s * u);
      }
    }
  }
}

// ---------------- grouped GEMM2: Y = h @ down^T (row space, bf16, plain stores) ----------------
__global__ __launch_bounds__(256, 4) void k_gemm2(
    const u16* __restrict__ hb, const u16* __restrict__ dwb,
    const int* __restrict__ meta, u16* __restrict__ Y)
{
  int total = meta[8];
  int tile = blockIdx.x;
  if (tile >= total) return;
  int e = meta[64 + tile];
  int row0 = meta[256 + tile];
  int ntile = blockIdx.y;

  __shared__ u16 As[BM * BK];
  __shared__ u16 Bs[BN * BK];

  int lane = threadIdx.x & 63;
  int wave = threadIdx.x >> 6;
  int wr = wave >> 1, wc = wave & 1;

  const u16* aG[4]; const u16* bG[4];
  unsigned ldsOff[4];
#pragma unroll
  for (int j = 0; j < 4; j++) {
    int r = wave * 32 + j * 8 + (lane >> 3);
    int c = (lane & 7) ^ (r & 7);
    aG[j] = hb + (size_t)(row0 + r) * FD + c * 8;
    int nrow = ntile * BN + r;
    bG[j] = dwb + ((size_t)e * HD + nrow) * FD + c * 8;
    ldsOff[j] = (unsigned)(wave * 32 + j * 8) * 128;
  }

  f32x4 acc[4][4] = {};

  for (int kt = 0; kt < FD / BK; kt++) {
    int ko = kt * BK;
#pragma unroll
    for (int j = 0; j < 4; j++) async_copy16(aG[j] + ko, (char*)As + ldsOff[j]);
#pragma unroll
    for (int j = 0; j < 4; j++) async_copy16(bG[j] + ko, (char*)Bs + ldsOff[j]);
    __syncthreads();
#pragma unroll
    for (int kk = 0; kk < 2; kk++) {
      bf16x8 av[4], bv[4];
#pragma unroll
      for (int mi = 0; mi < 4; mi++) {
        int r = wr * 64 + mi * 16 + (lane & 15);
        int slot = (kk * 4 + (lane >> 4)) ^ (r & 7);
        av[mi] = *(const bf16x8*)((const char*)As + (unsigned)(r * 8 + slot) * 16);
      }
#pragma unroll
      for (int ni = 0; ni < 4; ni++) {
        int r = wc * 64 + ni * 16 + (lane & 15);
        int slot = (kk * 4 + (lane >> 4)) ^ (r & 7);
        bv[ni] = *(const bf16x8*)((const char*)Bs + (unsigned)(r * 8 + slot) * 16);
      }
#pragma unroll
      for (int mi = 0; mi < 4; mi++)
#pragma unroll
        for (int ni = 0; ni < 4; ni++)
          acc[mi][ni] = __builtin_amdgcn_mfma_f32_16x16x32_bf16(av[mi], bv[ni], acc[mi][ni], 0, 0, 0);
    }
    __syncthreads();
  }

  // epilogue: plain bf16 stores into row-space Y (no atomics)
#pragma unroll
  for (int mi = 0; mi < 4; mi++) {
#pragma unroll
    for (int r = 0; r < 4; r++) {
      int grow = row0 + wr * 64 + mi * 16 + (lane >> 4) * 4 + r;
      u16* yrow = Y + (size_t)grow * HD + ntile * BN + wc * 64 + (lane & 15);
#pragma unroll
      for (int ni = 0; ni < 4; ni++)
        yrow[ni * 16] = f2bf(acc[mi][ni][r]);
    }
  }
}

// ---------------- combine: out[t] = wA*Y[rowA] + wB*Y[rowB] ----------------
__global__ __launch_bounds__(256) void k_combine(
    const u16* __restrict__ Y, const int* __restrict__ tokrow,
    const float* __restrict__ topk_w, float* __restrict__ out)
{
  int t = blockIdx.x;
  int i = threadIdx.x;               // 256 threads x 8 cols = 2048
  int rA = tokrow[t * 2], rB = tokrow[t * 2 + 1];
  float wA = topk_w[t * 2], wB = topk_w[t * 2 + 1];
  uint4 a = *(const uint4*)(Y + (size_t)rA * HD + i * 8);
  uint4 b = *(const uint4*)(Y + (size_t)rB * HD + i * 8);
  float4 o0, o1;
  o0.x = wA * bflo(a.x) + wB * bflo(b.x);
  o0.y = wA * bfhi(a.x) + wB * bfhi(b.x);
  o0.z = wA * bflo(a.y) + wB * bflo(b.y);
  o0.w = wA * bfhi(a.y) + wB * bfhi(b.y);
  o1.x = wA * bflo(a.z) + wB * bflo(b.z);
  o1.y = wA * bfhi(a.z) + wB * bfhi(b.z);
  o1.z = wA * bflo(a.w) + wB * bflo(b.w);
  o1.w = wA * bfhi(a.w) + wB * bfhi(b.w);
  float* op = out + (size_t)t * HD + i * 8;
  *(float4*)op = o0;
  *(float4*)(op + 4) = o1;
}

extern "C" void kernel_launch(void* const* d_in, const int* in_sizes, int n_in,
                              void* d_out, int out_size, void* d_ws, size_t ws_size,
                              hipStream_t stream) {
  const float* x  = (const float*)d_in[0];
  const float* rw = (const float*)d_in[1];
  const float* gw = (const float*)d_in[2];
  const float* uw = (const float*)d_in[3];
  const float* dw = (const float*)d_in[4];
  float* out = (float*)d_out;

  char* w = (char*)d_ws;
  int*   meta      = (int*)w;                                    // 4KB meta block
  int*   row_token = (int*)(w + 4096);
  int*   topk_idx  = (int*)(w + 4096 + ROWS_CAP * 4);
  float* topk_w    = (float*)(w + 4096 + ROWS_CAP * 4 + T_TOK * 2 * 4);
  int*   tokrow    = (int*)(w + 4096 + ROWS_CAP * 4 + T_TOK * 4 * 4);
  size_t off = (size_t)1 << 20;
  u16* xb  = (u16*)(w + off); off += (size_t)T_TOK * HD * 2;     // 33.5 MB
  u16* gwb = (u16*)(w + off); off += (size_t)NE * FD * HD * 2;   // 46.1 MB
  u16* uwb = (u16*)(w + off); off += (size_t)NE * FD * HD * 2;   // 46.1 MB
  u16* dwb = (u16*)(w + off); off += (size_t)NE * HD * FD * 2;   // 46.1 MB
  u16* hb  = (u16*)(w + off);                                    // 49.0 MB
  // Y (71.3 MB) aliases xb+gwb (79.7 MB) — both dead once gemm1 completes,
  // and the stream serializes gemm1 -> gemm2 -> combine.
  u16* Y = xb;

  k_convert_w<<<dim3(4096, 3), 256, 0, stream>>>(gw, uw, dw, gwb, uwb, dwb);

  k_router<<<T_TOK, 256, 0, stream>>>(x, rw, xb, topk_idx, topk_w);
  k_meta<<<1, 256, 0, stream>>>(topk_idx, meta, row_token);
  k_scatter<<<T_TOK / 256, 256, 0, stream>>>(topk_idx, meta, row_token, tokrow);

  k_gemm1<<<dim3(MAXT, FD / BN), 256, 0, stream>>>(xb, gwb, uwb, meta, row_token, hb);
  k_gemm2<<<dim3(MAXT, HD / BN), 256, 0, stream>>>(hb, dwb, meta, Y);
  k_combine<<<T_TOK, 256, 0, stream>>>(Y, tokrow, topk_w, out);
}

// Round 4
// 724.629 us; speedup vs baseline: 1.5126x; 1.0303x over previous
//
#include <hip/hip_runtime.h>
#include <stdint.h>

#define T_TOK 8192
#define HD 2048
#define NE 8
#define FD 1408
#define BM 128
#define BN 128
#define BK 64
#define MAXT 136            // max 128-row tiles: 16384/128 + 8
#define ROWS_CAP 17408      // 16384 + 8*128 padding

typedef unsigned short u16;
typedef __attribute__((ext_vector_type(8))) short bf16x8;   // 8 bf16 = 4 VGPRs
typedef __attribute__((ext_vector_type(4))) float f32x4;

__device__ __forceinline__ u16 f2bf(float f) {
  unsigned u = __float_as_uint(f);
  unsigned r = (u + 0x7fffu + ((u >> 16) & 1u)) >> 16;   // round-to-nearest-even
  return (u16)r;
}
__device__ __forceinline__ float bflo(unsigned u) { return __uint_as_float(u << 16); }
__device__ __forceinline__ float bfhi(unsigned u) { return __uint_as_float(u & 0xffff0000u); }

__device__ __forceinline__ void async_copy16(const void* g, void* l) {
  __builtin_amdgcn_global_load_lds(
      (__attribute__((address_space(1))) void*)(uintptr_t)g,
      (__attribute__((address_space(3))) void*)(uintptr_t)l,
      16, 0, 0);
}

__device__ __forceinline__ void conv4(const float* __restrict__ s, u16* __restrict__ d, long j) {
  float4 v = ((const float4*)s)[j];
  ushort4 o;
  o.x = f2bf(v.x); o.y = f2bf(v.y); o.z = f2bf(v.z); o.w = f2bf(v.w);
  ((ushort4*)d)[j] = o;
}

// ---------------- router (+ fused x->bf16 and weight fp32->bf16 conversion) ----------------
__global__ __launch_bounds__(256) void k_router(
    const float* __restrict__ x, const float* __restrict__ rw,
    const float* __restrict__ gw, const float* __restrict__ uw, const float* __restrict__ dw,
    u16* __restrict__ xb, u16* __restrict__ gwb, u16* __restrict__ uwb, u16* __restrict__ dwb,
    int* __restrict__ topk_idx, float* __restrict__ topk_w)
{
  int t = blockIdx.x;
  int tid = threadIdx.x;
  int lane = tid & 63;
  int wave = tid >> 6;               // wave w handles experts 2w, 2w+1
  const float4* xr = (const float4*)(x + (size_t)t * HD);
  const float4* w0 = (const float4*)(rw + (size_t)(wave * 2) * HD);
  const float4* w1 = (const float4*)(rw + (size_t)(wave * 2 + 1) * HD);
  float a0 = 0.f, a1 = 0.f;
  for (int i = lane; i < HD / 4; i += 64) {
    float4 xv = xr[i], v0 = w0[i], v1 = w1[i];
    a0 += xv.x * v0.x + xv.y * v0.y + xv.z * v0.z + xv.w * v0.w;
    a1 += xv.x * v1.x + xv.y * v1.y + xv.z * v1.z + xv.w * v1.w;
  }
  // fused x row -> bf16 (row is L1-hot)
  {
    float4 v0 = xr[tid * 2], v1 = xr[tid * 2 + 1];
    uint4 o;
    o.x = (unsigned)f2bf(v0.x) | ((unsigned)f2bf(v0.y) << 16);
    o.y = (unsigned)f2bf(v0.z) | ((unsigned)f2bf(v0.w) << 16);
    o.z = (unsigned)f2bf(v1.x) | ((unsigned)f2bf(v1.y) << 16);
    o.w = (unsigned)f2bf(v1.z) | ((unsigned)f2bf(v1.w) << 16);
    ((uint4*)(xb + (size_t)t * HD))[tid] = o;
  }
#pragma unroll
  for (int off = 32; off > 0; off >>= 1) {
    a0 += __shfl_down(a0, off);
    a1 += __shfl_down(a1, off);
  }
  __shared__ float lg[NE];
  if (lane == 0) { lg[wave * 2] = a0; lg[wave * 2 + 1] = a1; }
  __syncthreads();
  if (tid == 0) {
    float m1 = lg[0], m2 = -3.4e38f;
    int i1 = 0, i2 = 0;
    for (int e = 1; e < NE; e++) {
      float v = lg[e];
      if (v > m1)      { m2 = m1; i2 = i1; m1 = v; i1 = e; }
      else if (v > m2) { m2 = v; i2 = e; }
    }
    // normalized top-2 weights == 2-way softmax of top-2 logits
    float wA = 1.f / (1.f + expf(m2 - m1));
    float wB = 1.f - wA;
    topk_idx[t * 2] = i1; topk_idx[t * 2 + 1] = i2;
    topk_w[t * 2] = wA;   topk_w[t * 2 + 1] = wB;
  }
  // fused weight conversion: grid-stride over gate/up/down (overlaps router latency)
  const long n_w = (long)NE * FD * HD / 4;
  const long gstride = (long)gridDim.x * 256;
  const long g0 = (long)t * 256 + tid;
  for (long j = g0; j < n_w; j += gstride) conv4(gw, gwb, j);
  for (long j = g0; j < n_w; j += gstride) conv4(uw, uwb, j);
  for (long j = g0; j < n_w; j += gstride) conv4(dw, dwb, j);
}

// ---------------- meta+scatter: single block, prefix-scan, no global atomics ----------------
__global__ __launch_bounds__(256) void k_meta_scatter(
    const int* __restrict__ topk_idx, int* __restrict__ meta,
    int* __restrict__ row_token, int* __restrict__ tokrow)
{
  __shared__ int scan[NE][257];    // [e][0]=0; [e][tid+1]=thread count; then inclusive scan
  __shared__ int roff[NE], tstart[NE + 1];
  int tid = threadIdx.x;
  // zero row_token so padding rows map to token 0 (their Y rows are never read)
  for (int i = tid; i < ROWS_CAP; i += 256) row_token[i] = 0;
  if (tid < NE) scan[tid][0] = 0;
  // count: 64 contiguous items per thread
  int cnt[NE] = {};
  int base_i = tid * 64;
#pragma unroll 4
  for (int j = 0; j < 64; j++) {
    int v = topk_idx[base_i + j];
#pragma unroll
    for (int e = 0; e < NE; e++) cnt[e] += (v == e);
  }
  int i = tid + 1;
#pragma unroll
  for (int e = 0; e < NE; e++) scan[e][i] = cnt[e];
  __syncthreads();
  // Hillis-Steele inclusive scan over indices 1..256 (8 steps)
  for (int s = 1; s < 256; s <<= 1) {
    int add[NE];
#pragma unroll
    for (int e = 0; e < NE; e++) add[e] = (i >= s) ? scan[e][i - s] : 0;
    __syncthreads();
#pragma unroll
    for (int e = 0; e < NE; e++) scan[e][i] += add[e];
    __syncthreads();
  }
  if (tid == 0) {
    int off = 0, nt = 0;
    for (int e = 0; e < NE; e++) {
      int tot = scan[e][256];
      int tiles = (tot + BM - 1) / BM;
      roff[e] = off;
      tstart[e] = nt;
      nt += tiles;
      off += tiles * BM;           // expert regions padded to 128 rows
    }
    tstart[NE] = nt;
    meta[8] = nt;                  // total tiles
  }
  __syncthreads();
  int nt = tstart[NE];
  if (tid < nt) {
    int e = 0;
#pragma unroll
    for (int k = 1; k < NE; k++) e += (tid >= tstart[k]);
    meta[64 + tid] = e;                                 // tile -> expert
    meta[256 + tid] = roff[e] + (tid - tstart[e]) * BM; // tile -> row0
  }
  // placement: deterministic, no atomics
  int pos[NE];
#pragma unroll
  for (int e = 0; e < NE; e++) pos[e] = roff[e] + scan[e][tid];
  for (int j = 0; j < 64; j++) {
    int idx = base_i + j;
    int v = topk_idx[idx];
    int p = 0;
#pragma unroll
    for (int e = 0; e < NE; e++) if (v == e) p = pos[e]++;
    row_token[p] = idx >> 1;
    tokrow[idx] = p;
  }
}

// ---------------- grouped GEMM1: h = silu(x@gate^T) * (x@up^T), bf16 out ----------------
__global__ __launch_bounds__(256, 2) void k_gemm1(
    const u16* __restrict__ xb, const u16* __restrict__ gwb, const u16* __restrict__ uwb,
    const int* __restrict__ meta, const int* __restrict__ row_token, u16* __restrict__ hb)
{
  int total = meta[8];
  int tile = blockIdx.x;
  if (tile >= total) return;
  int e = meta[64 + tile];
  int row0 = meta[256 + tile];
  int ntile = blockIdx.y;

  __shared__ u16 As[BM * BK];   // XOR-swizzled at 16B-chunk granularity
  __shared__ u16 Bg[BN * BK];
  __shared__ u16 Bu[BN * BK];

  int lane = threadIdx.x & 63;
  int wave = threadIdx.x >> 6;
  int wr = wave >> 1, wc = wave & 1;

  const u16* aG[4]; const u16* gG[4]; const u16* uG[4];
  unsigned ldsOff[4];
#pragma unroll
  for (int j = 0; j < 4; j++) {
    int r = wave * 32 + j * 8 + (lane >> 3);
    int c = (lane & 7) ^ (r & 7);
    int tok = row_token[row0 + r];
    aG[j] = xb + (size_t)tok * HD + c * 8;
    int nrow = ntile * BN + r;
    size_t wof = ((size_t)e * FD + nrow) * HD + c * 8;
    gG[j] = gwb + wof;
    uG[j] = uwb + wof;
    ldsOff[j] = (unsigned)(wave * 32 + j * 8) * 128;  // wave-uniform LDS base
  }

  f32x4 accG[4][4] = {};
  f32x4 accU[4][4] = {};

  for (int kt = 0; kt < HD / BK; kt++) {
    int ko = kt * BK;
#pragma unroll
    for (int j = 0; j < 4; j++) async_copy16(aG[j] + ko, (char*)As + ldsOff[j]);
#pragma unroll
    for (int j = 0; j < 4; j++) async_copy16(gG[j] + ko, (char*)Bg + ldsOff[j]);
#pragma unroll
    for (int j = 0; j < 4; j++) async_copy16(uG[j] + ko, (char*)Bu + ldsOff[j]);
    __syncthreads();
#pragma unroll
    for (int kk = 0; kk < 2; kk++) {
      bf16x8 av[4], gv[4], uv[4];
#pragma unroll
      for (int mi = 0; mi < 4; mi++) {
        int r = wr * 64 + mi * 16 + (lane & 15);
        int slot = (kk * 4 + (lane >> 4)) ^ (r & 7);
        av[mi] = *(const bf16x8*)((const char*)As + (unsigned)(r * 8 + slot) * 16);
      }
#pragma unroll
      for (int ni = 0; ni < 4; ni++) {
        int r = wc * 64 + ni * 16 + (lane & 15);
        int slot = (kk * 4 + (lane >> 4)) ^ (r & 7);
        gv[ni] = *(const bf16x8*)((const char*)Bg + (unsigned)(r * 8 + slot) * 16);
        uv[ni] = *(const bf16x8*)((const char*)Bu + (unsigned)(r * 8 + slot) * 16);
      }
#pragma unroll
      for (int mi = 0; mi < 4; mi++)
#pragma unroll
        for (int ni = 0; ni < 4; ni++) {
          accG[mi][ni] = __builtin_amdgcn_mfma_f32_16x16x32_bf16(av[mi], gv[ni], accG[mi][ni], 0, 0, 0);
          accU[mi][ni] = __builtin_amdgcn_mfma_f32_16x16x32_bf16(av[mi], uv[ni], accU[mi][ni], 0, 0, 0);
        }
    }
    __syncthreads();
  }

  // epilogue: silu(g)*u -> bf16 h. D layout: col=lane&15, row=(lane>>4)*4+reg
#pragma unroll
  for (int mi = 0; mi < 4; mi++) {
#pragma unroll
    for (int r = 0; r < 4; r++) {
      int row = row0 + wr * 64 + mi * 16 + (lane >> 4) * 4 + r;
      u16* hrow = hb + (size_t)row * FD + ntile * BN + wc * 64 + (lane & 15);
#pragma unroll
      for (int ni = 0; ni < 4; ni++) {
        float g = accG[mi][ni][r];
        float u = accU[mi][ni][r];
        float s = g / (1.f + __expf(-g));
        hrow[ni * 16] = f2bf(s * u);
      }
    }
  }
}

// ---------------- grouped GEMM2: Y = h @ down^T (row space, bf16, plain stores) ----------------
// (256,3): 170 regs/wave budget -> 124 live regs fit WITHOUT spill; (256,4)'s
// 128-reg cap was right at the edge and likely spilled in the K-loop.
__global__ __launch_bounds__(256, 3) void k_gemm2(
    const u16* __restrict__ hb, const u16* __restrict__ dwb,
    const int* __restrict__ meta, u16* __restrict__ Y)
{
  int total = meta[8];
  int tile = blockIdx.x;
  if (tile >= total) return;
  int e = meta[64 + tile];
  int row0 = meta[256 + tile];
  int ntile = blockIdx.y;

  __shared__ u16 As[BM * BK];
  __shared__ u16 Bs[BN * BK];

  int lane = threadIdx.x & 63;
  int wave = threadIdx.x >> 6;
  int wr = wave >> 1, wc = wave & 1;

  const u16* aG[4]; const u16* bG[4];
  unsigned ldsOff[4];
#pragma unroll
  for (int j = 0; j < 4; j++) {
    int r = wave * 32 + j * 8 + (lane >> 3);
    int c = (lane & 7) ^ (r & 7);
    aG[j] = hb + (size_t)(row0 + r) * FD + c * 8;
    int nrow = ntile * BN + r;
    bG[j] = dwb + ((size_t)e * HD + nrow) * FD + c * 8;
    ldsOff[j] = (unsigned)(wave * 32 + j * 8) * 128;
  }

  f32x4 acc[4][4] = {};

  for (int kt = 0; kt < FD / BK; kt++) {
    int ko = kt * BK;
#pragma unroll
    for (int j = 0; j < 4; j++) async_copy16(aG[j] + ko, (char*)As + ldsOff[j]);
#pragma unroll
    for (int j = 0; j < 4; j++) async_copy16(bG[j] + ko, (char*)Bs + ldsOff[j]);
    __syncthreads();
#pragma unroll
    for (int kk = 0; kk < 2; kk++) {
      bf16x8 av[4], bv[4];
#pragma unroll
      for (int mi = 0; mi < 4; mi++) {
        int r = wr * 64 + mi * 16 + (lane & 15);
        int slot = (kk * 4 + (lane >> 4)) ^ (r & 7);
        av[mi] = *(const bf16x8*)((const char*)As + (unsigned)(r * 8 + slot) * 16);
      }
#pragma unroll
      for (int ni = 0; ni < 4; ni++) {
        int r = wc * 64 + ni * 16 + (lane & 15);
        int slot = (kk * 4 + (lane >> 4)) ^ (r & 7);
        bv[ni] = *(const bf16x8*)((const char*)Bs + (unsigned)(r * 8 + slot) * 16);
      }
#pragma unroll
      for (int mi = 0; mi < 4; mi++)
#pragma unroll
        for (int ni = 0; ni < 4; ni++)
          acc[mi][ni] = __builtin_amdgcn_mfma_f32_16x16x32_bf16(av[mi], bv[ni], acc[mi][ni], 0, 0, 0);
    }
    __syncthreads();
  }

  // epilogue: plain bf16 stores into row-space Y (no atomics)
#pragma unroll
  for (int mi = 0; mi < 4; mi++) {
#pragma unroll
    for (int r = 0; r < 4; r++) {
      int grow = row0 + wr * 64 + mi * 16 + (lane >> 4) * 4 + r;
      u16* yrow = Y + (size_t)grow * HD + ntile * BN + wc * 64 + (lane & 15);
#pragma unroll
      for (int ni = 0; ni < 4; ni++)
        yrow[ni * 16] = f2bf(acc[mi][ni][r]);
    }
  }
}

// ---------------- combine: out[t] = wA*Y[rowA] + wB*Y[rowB] ----------------
__global__ __launch_bounds__(256) void k_combine(
    const u16* __restrict__ Y, const int* __restrict__ tokrow,
    const float* __restrict__ topk_w, float* __restrict__ out)
{
  int t = blockIdx.x;
  int i = threadIdx.x;               // 256 threads x 8 cols = 2048
  int rA = tokrow[t * 2], rB = tokrow[t * 2 + 1];
  float wA = topk_w[t * 2], wB = topk_w[t * 2 + 1];
  uint4 a = *(const uint4*)(Y + (size_t)rA * HD + i * 8);
  uint4 b = *(const uint4*)(Y + (size_t)rB * HD + i * 8);
  float4 o0, o1;
  o0.x = wA * bflo(a.x) + wB * bflo(b.x);
  o0.y = wA * bfhi(a.x) + wB * bfhi(b.x);
  o0.z = wA * bflo(a.y) + wB * bflo(b.y);
  o0.w = wA * bfhi(a.y) + wB * bfhi(b.y);
  o1.x = wA * bflo(a.z) + wB * bflo(b.z);
  o1.y = wA * bfhi(a.z) + wB * bfhi(b.z);
  o1.z = wA * bflo(a.w) + wB * bflo(b.w);
  o1.w = wA * bfhi(a.w) + wB * bfhi(b.w);
  float* op = out + (size_t)t * HD + i * 8;
  *(float4*)op = o0;
  *(float4*)(op + 4) = o1;
}

extern "C" void kernel_launch(void* const* d_in, const int* in_sizes, int n_in,
                              void* d_out, int out_size, void* d_ws, size_t ws_size,
                              hipStream_t stream) {
  const float* x  = (const float*)d_in[0];
  const float* rw = (const float*)d_in[1];
  const float* gw = (const float*)d_in[2];
  const float* uw = (const float*)d_in[3];
  const float* dw = (const float*)d_in[4];
  float* out = (float*)d_out;

  char* w = (char*)d_ws;
  int*   meta      = (int*)w;                                    // 4KB meta block
  int*   row_token = (int*)(w + 4096);
  int*   topk_idx  = (int*)(w + 4096 + ROWS_CAP * 4);
  float* topk_w    = (float*)(w + 4096 + ROWS_CAP * 4 + T_TOK * 2 * 4);
  int*   tokrow    = (int*)(w + 4096 + ROWS_CAP * 4 + T_TOK * 4 * 4);
  size_t off = (size_t)1 << 20;
  u16* xb  = (u16*)(w + off); off += (size_t)T_TOK * HD * 2;     // 33.5 MB
  u16* gwb = (u16*)(w + off); off += (size_t)NE * FD * HD * 2;   // 46.1 MB
  u16* uwb = (u16*)(w + off); off += (size_t)NE * FD * HD * 2;   // 46.1 MB
  u16* dwb = (u16*)(w + off); off += (size_t)NE * HD * FD * 2;   // 46.1 MB
  u16* hb  = (u16*)(w + off);                                    // 49.0 MB
  // Y (71.3 MB) aliases xb+gwb (79.7 MB) — both dead once gemm1 completes,
  // and the stream serializes gemm1 -> gemm2 -> combine.
  u16* Y = xb;

  k_router<<<T_TOK, 256, 0, stream>>>(x, rw, gw, uw, dw, xb, gwb, uwb, dwb, topk_idx, topk_w);
  k_meta_scatter<<<1, 256, 0, stream>>>(topk_idx, meta, row_token, tokrow);
  k_gemm1<<<dim3(MAXT, FD / BN), 256, 0, stream>>>(xb, gwb, uwb, meta, row_token, hb);
  k_gemm2<<<dim3(MAXT, HD / BN), 256, 0, stream>>>(hb, dwb, meta, Y);
  k_combine<<<T_TOK, 256, 0, stream>>>(Y, tokrow, topk_w, out);
}